// Round 7
// baseline (427.369 us; speedup 1.0000x reference)
//
#include <hip/hip_runtime.h>
#include <hip/hip_bf16.h>

#define N_NODES 100000
#define N_EDGES 1600000
// F == H == 128

#define BK_SHIFT 9
#define BK_NODES 512
#define NBKT 196              // ceil(N_NODES / 512)
#define BCAP 9216             // static bucket capacity (mean 8192, +11 sigma)
#define EDGES_PER_BLK 8192
#define NBLK_EDGE ((N_EDGES + EDGES_PER_BLK - 1) / EDGES_PER_BLK)  // 196

typedef unsigned short ush8 __attribute__((ext_vector_type(8)));
typedef unsigned short ush4 __attribute__((ext_vector_type(4)));
typedef __bf16 bf8 __attribute__((ext_vector_type(8)));
typedef float f4 __attribute__((ext_vector_type(4)));

__device__ __forceinline__ float lrelu(float v) {
    return v >= 0.0f ? v : 0.01f * v;
}

// f32 -> bf16 (RNE)
__device__ __forceinline__ unsigned short f2bf(float f) {
    unsigned u = __builtin_bit_cast(unsigned, f);
    return (unsigned short)((u + 0x7FFFu + ((u >> 16) & 1u)) >> 16);
}
__device__ __forceinline__ float bfs(unsigned short u) {
    return __builtin_bit_cast(float, (unsigned)u << 16);
}

// ---------------- CSR build: 2 passes, static bucket bases ----------------

// pass 1: histogram + reserve + packed scatter into gapped bins
__global__ __launch_bounds__(256) void bucket_scatter2(const int* __restrict__ src,
                                                       const int* __restrict__ dst,
                                                       int* __restrict__ bcnt,
                                                       unsigned* __restrict__ binned) {
    __shared__ int h[NBKT];
    __shared__ int bbase[NBKT];
    int t = threadIdx.x;
    for (int i = t; i < NBKT; i += 256) h[i] = 0;
    __syncthreads();
    int base = blockIdx.x * EDGES_PER_BLK;
#pragma unroll 4
    for (int k = 0; k < EDGES_PER_BLK / 256; ++k) {
        int e = base + k * 256 + t;
        if (e < N_EDGES) atomicAdd(&h[dst[e] >> BK_SHIFT], 1);
    }
    __syncthreads();
    for (int i = t; i < NBKT; i += 256) {
        int c = h[i];
        bbase[i] = c ? atomicAdd(&bcnt[i], c) : 0;
        h[i] = 0;  // reuse as local cursor
    }
    __syncthreads();
#pragma unroll 4
    for (int k = 0; k < EDGES_PER_BLK / 256; ++k) {
        int e = base + k * 256 + t;
        if (e < N_EDGES) {
            int d = dst[e], s = src[e];
            int b = d >> BK_SHIFT;
            int p = bbase[b] + atomicAdd(&h[b], 1);
            if (p < BCAP)  // statically impossible overflow guard
                binned[b * BCAP + p] =
                    ((unsigned)s << BK_SHIFT) | (unsigned)(d & (BK_NODES - 1));
        }
    }
}

// pass 2: per bucket: histogram -> scan -> off/deg -> place csr (gapped layout)
__global__ __launch_bounds__(256) void bucket_place2(const unsigned* __restrict__ binned,
                                                     const int* __restrict__ bcnt,
                                                     int* __restrict__ off,
                                                     int* __restrict__ deg,
                                                     int* __restrict__ csr) {
    __shared__ int hist[BK_NODES];
    __shared__ int pair[256];
    int b = blockIdx.x, t = threadIdx.x;
    int e0 = b * BCAP;
    int cnt = bcnt[b];
    cnt = (cnt < BCAP) ? cnt : BCAP;
    int e1 = e0 + cnt;
    hist[t] = 0;
    hist[t + 256] = 0;
    __syncthreads();
    for (int e = e0 + t; e < e1; e += 256)
        atomicAdd(&hist[binned[e] & (BK_NODES - 1)], 1);
    __syncthreads();
    int h0 = hist[2 * t], h1 = hist[2 * t + 1];
    pair[t] = h0 + h1;
    __syncthreads();
    for (int d = 1; d < 256; d <<= 1) {
        int a = (t >= d) ? pair[t - d] : 0;
        __syncthreads();
        pair[t] += a;
        __syncthreads();
    }
    int ep = pair[t] - (h0 + h1);
    int ex0 = ep, ex1 = ep + h0;
    int node0 = b * BK_NODES + 2 * t;
    if (node0 < N_NODES) {
        off[node0] = e0 + ex0;
        deg[node0] = h0;
    }
    if (node0 + 1 < N_NODES) {
        off[node0 + 1] = e0 + ex1;
        deg[node0 + 1] = h1;
    }
    __syncthreads();
    hist[2 * t] = ex0;  // reuse as relative cursors
    hist[2 * t + 1] = ex1;
    __syncthreads();
    for (int e = e0 + t; e < e1; e += 256) {
        unsigned v = binned[e];
        int dl = v & (BK_NODES - 1);
        int p = atomicAdd(&hist[dl], 1);
        csr[e0 + p] = (int)(v >> BK_SHIFT);
    }
}

// ---------------- weights ----------------
// W1T: true-k layout   W1T[col][k] = W1[k][col]
// W2T: permuted-k      W2T[col][q] = W2[k(q)][col],  k(q) = 16*(q&7) + (q>>3)
__global__ void wcast(const float* __restrict__ W1, const float* __restrict__ W2,
                      unsigned short* __restrict__ W1T, unsigned short* __restrict__ W2T) {
    int i = blockIdx.x * 256 + threadIdx.x;
    if (i >= 2 * 16384) return;
    int ii = i & 16383;
    int col = ii >> 7, q = ii & 127;
    if (i < 16384) {
        W1T[ii] = f2bf(W1[q * 128 + col]);
    } else {
        int k = 16 * (q & 7) + (q >> 3);
        W2T[ii] = f2bf(W2[k * 128 + col]);
    }
}

// ---------------- fc1: hB = bf16(lrelu(x @ W1 + b1)), permuted cols ----------------
__global__ __launch_bounds__(256) void gemm_fc1(
    const float* __restrict__ A, const unsigned short* __restrict__ WT,
    const float* __restrict__ bias, unsigned short* __restrict__ outB) {
    __shared__ unsigned short wlds[128][136];
    const int tid = threadIdx.x;
#pragma unroll
    for (int it = 0; it < 8; ++it) {
        int idx = it * 256 + tid;
        int r = idx >> 4, c = (idx & 15) << 3;
        *reinterpret_cast<ush8*>(&wlds[r][c]) =
            *reinterpret_cast<const ush8*>(&WT[r * 128 + c]);
    }

    const int lane = tid & 63, wave = tid >> 6;
    const int row0 = blockIdx.x * 64 + wave * 16;
    const int rl = lane & 15, kg = lane >> 4;
    int arow = row0 + rl;
    if (arow >= N_NODES) arow = N_NODES - 1;

    bf8 af[4];
#pragma unroll
    for (int kk = 0; kk < 4; ++kk) {
        const float* p = &A[arow * 128 + kk * 32 + kg * 8];
        float4 f0 = *reinterpret_cast<const float4*>(p);
        float4 f1 = *reinterpret_cast<const float4*>(p + 4);
        ush8 v;
        v[0] = f2bf(f0.x); v[1] = f2bf(f0.y); v[2] = f2bf(f0.z); v[3] = f2bf(f0.w);
        v[4] = f2bf(f1.x); v[5] = f2bf(f1.y); v[6] = f2bf(f1.z); v[7] = f2bf(f1.w);
        af[kk] = __builtin_bit_cast(bf8, v);
    }

    __syncthreads();

    f4 acc[8];
#pragma unroll
    for (int jt = 0; jt < 8; ++jt) acc[jt] = (f4)(0.0f);
#pragma unroll
    for (int jt = 0; jt < 8; ++jt) {
#pragma unroll
        for (int kk = 0; kk < 4; ++kk) {
            bf8 bfr = __builtin_bit_cast(
                bf8, *reinterpret_cast<const ush8*>(&wlds[jt * 16 + rl][kk * 32 + kg * 8]));
            acc[jt] = __builtin_amdgcn_mfma_f32_16x16x32_bf16(af[kk], bfr, acc[jt], 0, 0, 0);
        }
    }

    float bb[8];
#pragma unroll
    for (int j = 0; j < 8; ++j) bb[j] = bias[j * 16 + rl];

#pragma unroll
    for (int i = 0; i < 4; ++i) {
        int r = row0 + kg * 4 + i;
        if (r < N_NODES) {
            ush8 sv;
#pragma unroll
            for (int j = 0; j < 8; ++j) sv[j] = f2bf(lrelu(acc[j][i] + bb[j]));
            *reinterpret_cast<ush8*>(&outB[r * 128 + rl * 8]) = sv;
        }
    }
}

// ---------------- fused: agg (gather->LDS) + GEMM + residual + lrelu ----------------
// 512 threads (8 waves), 64 rows/block. Reads hOld (gather + residual, permuted
// layout), writes hNew (permuted bf16) or out (f32, true layout) when FINAL.
// Wave w: agg rows w*8..w*8+8; GEMM rows (w&3)*16..+16, jt-half (w>>2)*4..+4.
template <bool FINAL>
__global__ __launch_bounds__(512) void fused_agg_gemm(
    const unsigned short* __restrict__ hOld, const int* __restrict__ off,
    const int* __restrict__ deg, const int* __restrict__ csr,
    const unsigned short* __restrict__ WT, const float* __restrict__ bias,
    float* __restrict__ outF, unsigned short* __restrict__ outB) {
    __shared__ unsigned short wlds[128][136];
    __shared__ unsigned mlds[64][68];  // packed bf16x2; 16B-aligned rows
    const int tid = threadIdx.x;
    const int lane = tid & 63, wave = tid >> 6;
    const int r0 = blockIdx.x * 64;

    // stage W: 512 threads x 4 chunks of ush8
#pragma unroll
    for (int it = 0; it < 4; ++it) {
        int idx = it * 512 + tid;
        int r = idx >> 4, c = (idx & 15) << 3;
        *reinterpret_cast<ush8*>(&wlds[r][c]) =
            *reinterpret_cast<const ush8*>(&WT[r * 128 + c]);
    }

    // agg phase: wave handles 8 rows; lane owns packed positions {2*lane, 2*lane+1}
    const unsigned* hb = reinterpret_cast<const unsigned*>(hOld);  // [N][64] u32
#pragma unroll
    for (int rr = 0; rr < 8; ++rr) {
        int row = r0 + wave * 8 + rr;
        if (row < N_NODES) {
            int e0 = off[row];
            int dgr = deg[row];
            int e1 = e0 + dgr;
            float ax = 0.0f, ay = 0.0f;
            int e = e0;
            for (; e + 16 <= e1; e += 16) {
                int s[16];
#pragma unroll
                for (int k = 0; k < 16; ++k) s[k] = csr[e + k];
#pragma unroll
                for (int k = 0; k < 16; ++k) {
                    unsigned u = hb[s[k] * 64 + lane];
                    ax += __builtin_bit_cast(float, u << 16);
                    ay += __builtin_bit_cast(float, u & 0xFFFF0000u);
                }
            }
            for (; e + 8 <= e1; e += 8) {
                int s[8];
#pragma unroll
                for (int k = 0; k < 8; ++k) s[k] = csr[e + k];
#pragma unroll
                for (int k = 0; k < 8; ++k) {
                    unsigned u = hb[s[k] * 64 + lane];
                    ax += __builtin_bit_cast(float, u << 16);
                    ay += __builtin_bit_cast(float, u & 0xFFFF0000u);
                }
            }
            for (; e + 2 <= e1; e += 2) {
                unsigned u0 = hb[csr[e] * 64 + lane];
                unsigned u1 = hb[csr[e + 1] * 64 + lane];
                ax += __builtin_bit_cast(float, u0 << 16) +
                      __builtin_bit_cast(float, u1 << 16);
                ay += __builtin_bit_cast(float, u0 & 0xFFFF0000u) +
                      __builtin_bit_cast(float, u1 & 0xFFFF0000u);
            }
            if (e < e1) {
                unsigned u = hb[csr[e] * 64 + lane];
                ax += __builtin_bit_cast(float, u << 16);
                ay += __builtin_bit_cast(float, u & 0xFFFF0000u);
            }
            float inv = (dgr > 0) ? 1.0f / (float)dgr : 0.0f;
            mlds[wave * 8 + rr][lane] =
                ((unsigned)f2bf(ay * inv) << 16) | (unsigned)f2bf(ax * inv);
        }
    }

    __syncthreads();

    // GEMM phase
    const int rl = lane & 15, kg = lane >> 4;
    const int jh = (wave >> 2) * 4;          // jt half: 0 or 4
    const int lrow = (wave & 3) * 16 + rl;   // local A row 0..63

    bf8 af[4];
#pragma unroll
    for (int kk = 0; kk < 4; ++kk)
        af[kk] = __builtin_bit_cast(
            bf8, *reinterpret_cast<const ush8*>(&mlds[lrow][kk * 16 + kg * 4]));

    f4 acc[4];
#pragma unroll
    for (int j = 0; j < 4; ++j) acc[j] = (f4)(0.0f);
#pragma unroll
    for (int j = 0; j < 4; ++j) {
        int jt = jh + j;
#pragma unroll
        for (int kk = 0; kk < 4; ++kk) {
            bf8 bfr = __builtin_bit_cast(
                bf8, *reinterpret_cast<const ush8*>(&wlds[jt * 16 + rl][kk * 32 + kg * 8]));
            acc[j] = __builtin_amdgcn_mfma_f32_16x16x32_bf16(af[kk], bfr, acc[j], 0, 0, 0);
        }
    }

    float bb[4];
#pragma unroll
    for (int j = 0; j < 4; ++j) bb[j] = bias[(jh + j) * 16 + rl];

#pragma unroll
    for (int i = 0; i < 4; ++i) {
        int r = r0 + (wave & 3) * 16 + kg * 4 + i;
        if (r < N_NODES) {
            // residual: positions rl*8 + jh .. +4 (8B aligned)
            ush4 rv = *reinterpret_cast<const ush4*>(&hOld[r * 128 + rl * 8 + jh]);
            float v[4];
#pragma unroll
            for (int j = 0; j < 4; ++j)
                v[j] = lrelu(acc[j][i] + bb[j] + bfs(rv[j]));
            if (FINAL) {
#pragma unroll
                for (int j = 0; j < 4; ++j)
                    outF[r * 128 + (jh + j) * 16 + rl] = v[j];
            } else {
                ush4 sv;
#pragma unroll
                for (int j = 0; j < 4; ++j) sv[j] = f2bf(v[j]);
                *reinterpret_cast<ush4*>(&outB[r * 128 + rl * 8 + jh]) = sv;
            }
        }
    }
}

// ---------------- launch ----------------

extern "C" void kernel_launch(void* const* d_in, const int* in_sizes, int n_in,
                              void* d_out, int out_size, void* d_ws, size_t ws_size,
                              hipStream_t stream) {
    const float* x  = (const float*)d_in[0];
    const float* W1 = (const float*)d_in[1];
    const float* b1 = (const float*)d_in[2];
    const float* W2 = (const float*)d_in[3];
    const float* b2 = (const float*)d_in[4];
    const int* esrc = (const int*)d_in[5];
    const int* edst = (const int*)d_in[6];
    float* out = (float*)d_out;

    char* ws = (char*)d_ws;
    size_t o = 0;
    auto alloc = [&](size_t b) {
        void* p = ws + o;
        o += (b + 511) & ~(size_t)511;
        return p;
    };
    int* bcnt = (int*)alloc(NBKT * 4);
    int* off  = (int*)alloc((size_t)N_NODES * 4);
    int* deg  = (int*)alloc((size_t)N_NODES * 4);
    int* csr  = (int*)alloc((size_t)NBKT * BCAP * 4);  // gapped layout
    unsigned short* W1T = (unsigned short*)alloc(128 * 128 * 2);
    unsigned short* W2T = (unsigned short*)alloc(128 * 128 * 2);
    unsigned short* hA = (unsigned short*)alloc((size_t)N_NODES * 128 * 2);
    unsigned short* hC = (unsigned short*)alloc((size_t)N_NODES * 128 * 2);
    unsigned* binned = (unsigned*)hC;  // alias: binned dead before hC first written

    hipMemsetAsync(bcnt, 0, NBKT * 4, stream);
    bucket_scatter2<<<NBLK_EDGE, 256, 0, stream>>>(esrc, edst, bcnt, binned);
    bucket_place2<<<NBKT, 256, 0, stream>>>(binned, bcnt, off, deg, csr);

    wcast<<<(2 * 16384 + 255) / 256, 256, 0, stream>>>(W1, W2, W1T, W2T);

    const int GB = (N_NODES + 63) / 64;  // 1563
    gemm_fc1<<<GB, 256, 0, stream>>>(x, W1T, b1, hA);

    // double-buffered iterations (synchronous update)
    fused_agg_gemm<false><<<GB, 512, 0, stream>>>(hA, off, deg, csr, W2T, b2,
                                                  nullptr, hC);
    fused_agg_gemm<false><<<GB, 512, 0, stream>>>(hC, off, deg, csr, W2T, b2,
                                                  nullptr, hA);
    fused_agg_gemm<true><<<GB, 512, 0, stream>>>(hA, off, deg, csr, W2T, b2,
                                                 out, nullptr);
}